// Round 3
// baseline (1326.623 us; speedup 1.0000x reference)
//
#include <hip/hip_runtime.h>

namespace {

typedef __attribute__((ext_vector_type(4))) _Float16 half4v;
typedef __attribute__((ext_vector_type(4))) float   float4v;
typedef unsigned int u32;

#define MFMA16(a,b,c) __builtin_amdgcn_mfma_f32_16x16x16f16((a),(b),(c),0,0,0)

constexpr int Bb = 2048;
constexpr int Tt = 512;
constexpr float LOG2PI_ = 1.8378770664093453f;

struct InPtrs { const float* p[42]; };

__device__ __forceinline__ float rcpf(float x){ return __builtin_amdgcn_rcpf(x); }
__device__ __forceinline__ float sigm(float x){ return rcpf(1.0f + __expf(-x)); }
__device__ __forceinline__ float tanh_(float x){ return 1.0f - 2.0f*rcpf(1.0f + __expf(2.0f*x)); }

__global__ void zero2(float* out){ if (threadIdx.x < 2) out[threadIdx.x] = 0.f; }

__device__ __forceinline__ void gru_update(const float4v& Dr, const float4v& Dz,
                                           const float4v& Dn, const float4v& Dh, half4v& hB){
  #pragma unroll
  for (int i = 0; i < 4; ++i){
    const float rr = sigm(Dr[i]);
    const float zz = sigm(Dz[i]);
    const float nn = tanh_(Dn[i] + rr*Dh[i]);
    const float hp = (float)hB[i];
    hB[i] = (_Float16)(nn + zz*(hp - nn));
  }
}

__device__ __forceinline__ half4v relu_pack(const float4v& D){
  half4v o;
  #pragma unroll
  for (int i = 0; i < 4; ++i) o[i] = (_Float16)fmaxf(D[i], 0.f);
  return o;
}

// ================= Phase 1: bi-GRU, single wave per (tile, dir) =================
// No LDS, no barriers. gi = Wih@x built from a depth-4 x register ring as two
// 2-deep MFMA trees; hB recurrence folded in last (chain from hB = 1 MFMA + gru).
__global__ __launch_bounds__(64,1) void bigru(InPtrs ip, _Float16* __restrict__ hf,
                                              _Float16* __restrict__ hb)
{
  const int l = threadIdx.x & 63, r = l & 15, q = l >> 4;
  const int dir = blockIdx.y;
  const int base = blockIdx.x * 16;

  const float* __restrict__ x   = ip.p[0];
  const float* __restrict__ Wih = dir ? ip.p[6] : ip.p[2];
  const float* __restrict__ Whh = dir ? ip.p[7] : ip.p[3];
  const float* __restrict__ bih = dir ? ip.p[8] : ip.p[4];
  const float* __restrict__ bhh = dir ? ip.p[9] : ip.p[5];
  _Float16* __restrict__ hout = dir ? hb : hf;

  half4v Wi[3][4], Wh[3];
  float  b0[4], b1[4], b2[4], bh2[4];
  float4v xp[4][4];              // depth-4 x prefetch ring
  half4v hB = {0,0,0,0};
  const float* xrow = x + (size_t)(base + r) * Tt * 64;

  #pragma unroll
  for (int rt = 0; rt < 3; ++rt)
    #pragma unroll
    for (int kt = 0; kt < 4; ++kt)
      #pragma unroll
      for (int j = 0; j < 4; ++j)
        Wi[rt][kt][j] = (_Float16)Wih[(rt*16 + r)*64 + kt*16 + q*4 + j];
  #pragma unroll
  for (int rt = 0; rt < 3; ++rt)
    #pragma unroll
    for (int j = 0; j < 4; ++j)
      Wh[rt][j] = (_Float16)Whh[(rt*16 + r)*16 + q*4 + j];
  #pragma unroll
  for (int i = 0; i < 4; ++i){
    const int row = q*4 + i;
    b0[i] = bih[row]      + bhh[row];
    b1[i] = bih[16 + row] + bhh[16 + row];
    b2[i] = bih[32 + row];
    bh2[i] = bhh[32 + row];
  }
  #pragma unroll
  for (int s = 0; s < 4; ++s){
    const int tn = dir ? Tt-1-s : s;
    #pragma unroll
    for (int kt = 0; kt < 4; ++kt)
      xp[s][kt] = *(const float4v*)(xrow + (size_t)tn*64 + kt*16 + q*4);
  }

  for (int ib = 0; ib < Tt; ib += 4){
    #pragma unroll
    for (int k = 0; k < 4; ++k){
      const int tg = ib + k;
      const int t = dir ? Tt-1-tg : tg;
      half4v xB[4];
      #pragma unroll
      for (int kt = 0; kt < 4; ++kt)
        #pragma unroll
        for (int j = 0; j < 4; ++j) xB[kt][j] = (_Float16)xp[k][kt][j];
      const int tp = tg + 4;
      if (tp < Tt){
        const int tn = dir ? Tt-1-tp : tp;
        #pragma unroll
        for (int kt = 0; kt < 4; ++kt)
          xp[k][kt] = *(const float4v*)(xrow + (size_t)tn*64 + kt*16 + q*4);
      }
      // gi as two 2-deep chains per gate, then hB folded in last
      float4v A0 = {b0[0],b0[1],b0[2],b0[3]};
      float4v A1 = {b1[0],b1[1],b1[2],b1[3]};
      float4v A2 = {b2[0],b2[1],b2[2],b2[3]};
      float4v A0x = {0,0,0,0}, A1x = {0,0,0,0}, A2x = {0,0,0,0};
      A0 = MFMA16(Wi[0][0], xB[0], A0); A0 = MFMA16(Wi[0][1], xB[1], A0);
      A1 = MFMA16(Wi[1][0], xB[0], A1); A1 = MFMA16(Wi[1][1], xB[1], A1);
      A2 = MFMA16(Wi[2][0], xB[0], A2); A2 = MFMA16(Wi[2][1], xB[1], A2);
      A0x = MFMA16(Wi[0][2], xB[2], A0x); A0x = MFMA16(Wi[0][3], xB[3], A0x);
      A1x = MFMA16(Wi[1][2], xB[2], A1x); A1x = MFMA16(Wi[1][3], xB[3], A1x);
      A2x = MFMA16(Wi[2][2], xB[2], A2x); A2x = MFMA16(Wi[2][3], xB[3], A2x);
      #pragma unroll
      for (int ii = 0; ii < 4; ++ii){ A0[ii] += A0x[ii]; A1[ii] += A1x[ii]; A2[ii] += A2x[ii]; }
      float4v Dh = {bh2[0],bh2[1],bh2[2],bh2[3]};
      A0 = MFMA16(Wh[0], hB, A0);
      A1 = MFMA16(Wh[1], hB, A1);
      Dh = MFMA16(Wh[2], hB, Dh);
      gru_update(A0, A1, A2, Dh, hB);
      *(half4v*)(hout + (((size_t)t*Bb + base + r) << 4) + q*4) = hB;
    }
  }
}

// ================= Phase 3a: fully fused sequential VAE, single wave per tile ==========
// All three recurrences + inf head in ONE wave: z stays in registers, no LDS,
// no barriers. genz/infz use z(s-1) (register), genr uses z(s) (just computed).
// Heads / KL / NLL still recomputed bit-identically in the parallel epilogue.
__global__ __launch_bounds__(64,1) void vae_fused(InPtrs ip, const _Float16* __restrict__ hf,
                                                  const _Float16* __restrict__ hb,
                                                  _Float16* __restrict__ hz,
                                                  _Float16* __restrict__ hgz,
                                                  _Float16* __restrict__ hgr)
{
  const int l = threadIdx.x & 63, r = l & 15, q = l >> 4;
  const int base = blockIdx.x * 16;
  const int row0 = q*4;

  // infz
  half4v WizA[3][3], WhzA[3], I1A, I2A, IMuA, ICovA;
  float bz0[4], bz1[4], bzn[4], bzh[4], bI1v[4], bI2v[4], bIMu[4], bICov[4];
  // genz
  half4v WgzA[3], WhgzA[3];
  float bg0[4], bg1[4], bgn[4], bgh[4];
  // genr
  half4v WgrA[3], WhgrA[3];
  float br0[4], br1[4], brn[4], brh[4];
  // state
  half4v hzB = {0,0,0,0}, hgzB = {0,0,0,0}, hgrB = {0,0,0,0}, zB = {0,0,0,0};
  half4v hrR[4], hlR[4];
  float4v eR[4];

  const float* erow = ip.p[1] + (size_t)(base + r) * Tt * 10;
  // clamped e column index: rows >=10 read row 9 (always in-bounds); the garbage
  // z-rows >=10 are multiplied by zeroed weight columns everywhere downstream.
  int eo[4];
  #pragma unroll
  for (int ii = 0; ii < 4; ++ii) eo[ii] = (row0 + ii < 10) ? (row0 + ii) : 9;

  #pragma unroll
  for (int rt = 0; rt < 3; ++rt)
    #pragma unroll
    for (int kt = 0; kt < 3; ++kt)
      #pragma unroll
      for (int j = 0; j < 4; ++j){
        const int k = kt*16 + q*4 + j;
        int c;
        if (kt == 0) c = (k < 10) ? k : -1;
        else if (kt == 1) c = 10 + (k - 16);
        else c = 26 + (k - 32);
        WizA[rt][kt][j] = (c >= 0) ? (_Float16)ip.p[10][(rt*16 + r)*42 + c] : (_Float16)0.f;
      }
  #pragma unroll
  for (int rt = 0; rt < 3; ++rt)
    #pragma unroll
    for (int j = 0; j < 4; ++j){
      const int k = q*4 + j;
      WhzA[rt][j]  = (_Float16)ip.p[11][(rt*16 + r)*16 + k];
      WgzA[rt][j]  = (k < 10) ? (_Float16)ip.p[22][(rt*16 + r)*10 + k] : (_Float16)0.f;
      WhgzA[rt][j] = (_Float16)ip.p[23][(rt*16 + r)*16 + k];
      WgrA[rt][j]  = (k < 10) ? (_Float16)ip.p[34][(rt*16 + r)*10 + k] : (_Float16)0.f;
      WhgrA[rt][j] = (_Float16)ip.p[35][(rt*16 + r)*16 + k];
    }
  #pragma unroll
  for (int j = 0; j < 4; ++j){
    const int k = q*4 + j;
    I1A[j]  = (_Float16)ip.p[14][r*16 + k];
    I2A[j]  = (_Float16)ip.p[16][r*16 + k];
    IMuA[j] = (r < 10) ? (_Float16)ip.p[18][r*16 + k] : (_Float16)0.f;
    ICovA[j]= (r < 10) ? (_Float16)ip.p[20][r*16 + k] : (_Float16)0.f;
  }
  #pragma unroll
  for (int i = 0; i < 4; ++i){
    const int row = row0 + i;
    bz0[i] = ip.p[12][row]    + ip.p[13][row];
    bz1[i] = ip.p[12][16+row] + ip.p[13][16+row];
    bzn[i] = ip.p[12][32+row];
    bzh[i] = ip.p[13][32+row];
    bI1v[i] = ip.p[15][row];  bI2v[i] = ip.p[17][row];
    bIMu[i]  = (row < 10) ? ip.p[19][row] : 0.f;
    bICov[i] = (row < 10) ? ip.p[21][row] : 0.f;
    bg0[i] = ip.p[24][row]    + ip.p[25][row];
    bg1[i] = ip.p[24][16+row] + ip.p[25][16+row];
    bgn[i] = ip.p[24][32+row];
    bgh[i] = ip.p[25][32+row];
    br0[i] = ip.p[36][row]    + ip.p[37][row];
    br1[i] = ip.p[36][16+row] + ip.p[37][16+row];
    brn[i] = ip.p[36][32+row];
    brh[i] = ip.p[37][32+row];
  }
  // preload ring: steps 0..3
  #pragma unroll
  for (int s = 0; s < 4; ++s){
    if (s >= 1) hrR[s] = *(const half4v*)(hf + (((size_t)(s-1)*Bb + base + r) << 4) + q*4);
    else { half4v z0 = {0,0,0,0}; hrR[s] = z0; }
    hlR[s] = *(const half4v*)(hb + (((size_t)(s+1)*Bb + base + r) << 4) + q*4);
    float4v et;
    #pragma unroll
    for (int ii = 0; ii < 4; ++ii) et[ii] = erow[s*10 + eo[ii]];
    eR[s] = et;
  }

  for (int ib = 0; ib < Tt; ib += 4){
    #pragma unroll
    for (int k = 0; k < 4; ++k){
      const int i = ib + k;
      const half4v hrB = hrR[k], hlB = hlR[k];
      const float4v ev = eR[k];
      const int f = i + 4;
      if (f < Tt){
        hrR[k] = *(const half4v*)(hf + (((size_t)(f-1)*Bb + base + r) << 4) + q*4);
        if (f <= Tt-2) hlR[k] = *(const half4v*)(hb + (((size_t)(f+1)*Bb + base + r) << 4) + q*4);
        else { half4v z0 = {0,0,0,0}; hlR[k] = z0; }
        float4v et;
        #pragma unroll
        for (int ii = 0; ii < 4; ++ii) et[ii] = erow[f*10 + eo[ii]];
        eR[k] = et;
      }

      // ---- genz (all inputs ready: zB = z(i-1), hgzB) ----
      float4v Er = {bg0[0],bg0[1],bg0[2],bg0[3]};
      float4v Ez = {bg1[0],bg1[1],bg1[2],bg1[3]};
      float4v En = {bgn[0],bgn[1],bgn[2],bgn[3]};
      float4v Eh = {bgh[0],bgh[1],bgh[2],bgh[3]};
      Er = MFMA16(WgzA[0], zB, Er); Er = MFMA16(WhgzA[0], hgzB, Er);
      Ez = MFMA16(WgzA[1], zB, Ez); Ez = MFMA16(WhgzA[1], hgzB, Ez);
      En = MFMA16(WgzA[2], zB, En);
      Eh = MFMA16(WhgzA[2], hgzB, Eh);

      // ---- infz (split accumulators: two 2-deep chains per gate) ----
      float4v Dr = {bz0[0],bz0[1],bz0[2],bz0[3]};
      float4v Dz = {bz1[0],bz1[1],bz1[2],bz1[3]};
      float4v Dn = {bzn[0],bzn[1],bzn[2],bzn[3]};
      float4v Dh = {bzh[0],bzh[1],bzh[2],bzh[3]};
      float4v DrX = {0,0,0,0}, DzX = {0,0,0,0}, DnX = {0,0,0,0};
      Dr = MFMA16(WizA[0][1], hrB, Dr); Dr = MFMA16(WhzA[0], hzB, Dr);
      Dz = MFMA16(WizA[1][1], hrB, Dz); Dz = MFMA16(WhzA[1], hzB, Dz);
      Dn = MFMA16(WizA[2][1], hrB, Dn); Dn = MFMA16(WizA[2][2], hlB, Dn);
      DrX = MFMA16(WizA[0][2], hlB, DrX); DrX = MFMA16(WizA[0][0], zB, DrX);
      DzX = MFMA16(WizA[1][2], hlB, DzX); DzX = MFMA16(WizA[1][0], zB, DzX);
      DnX = MFMA16(WizA[2][0], zB, DnX);
      Dh = MFMA16(WhzA[2], hzB, Dh);
      #pragma unroll
      for (int ii = 0; ii < 4; ++ii){ Dr[ii] += DrX[ii]; Dz[ii] += DzX[ii]; Dn[ii] += DnX[ii]; }
      gru_update(Dr, Dz, Dn, Dh, hzB);
      *(half4v*)(hz + (((size_t)i*Bb + base + r) << 4) + q*4) = hzB;

      // ---- genz finish (overlaps head below in the scheduler) ----
      gru_update(Er, Ez, En, Eh, hgzB);
      *(half4v*)(hgz + (((size_t)i*Bb + base + r) << 4) + q*4) = hgzB;

      // ---- inf head -> z ----
      float4v H1 = {bI1v[0],bI1v[1],bI1v[2],bI1v[3]};
      H1 = MFMA16(I1A, hzB, H1);
      const half4v h1B = relu_pack(H1);
      float4v H2 = {bI2v[0],bI2v[1],bI2v[2],bI2v[3]};
      H2 = MFMA16(I2A, h1B, H2);
      const half4v h2B = relu_pack(H2);
      float4v Qmu  = {bIMu[0],bIMu[1],bIMu[2],bIMu[3]};
      float4v Qpre = {bICov[0],bICov[1],bICov[2],bICov[3]};
      Qmu  = MFMA16(IMuA,  h2B, Qmu);
      Qpre = MFMA16(ICovA, h2B, Qpre);
      half4v zN;
      #pragma unroll
      for (int ii = 0; ii < 4; ++ii)
        zN[ii] = (_Float16)(Qmu[ii] + __expf(Qpre[ii])*ev[ii]);

      // ---- genr (uses z(i) = zN) ----
      float4v Fr = {br0[0],br0[1],br0[2],br0[3]};
      float4v Fz = {br1[0],br1[1],br1[2],br1[3]};
      float4v Fn = {brn[0],brn[1],brn[2],brn[3]};
      float4v Fh = {brh[0],brh[1],brh[2],brh[3]};
      Fr = MFMA16(WgrA[0], zN, Fr); Fr = MFMA16(WhgrA[0], hgrB, Fr);
      Fz = MFMA16(WgrA[1], zN, Fz); Fz = MFMA16(WhgrA[1], hgrB, Fz);
      Fn = MFMA16(WgrA[2], zN, Fn);
      Fh = MFMA16(WhgrA[2], hgrB, Fh);
      gru_update(Fr, Fz, Fn, Fh, hgrB);
      *(half4v*)(hgr + (((size_t)i*Bb + base + r) << 4) + q*4) = hgrB;

      zB = zN;
    }
  }
}

// ================= Phase 3b: merged parallel epilogue =================
__global__ __launch_bounds__(256,2) void epi(InPtrs ip, const _Float16* __restrict__ hz,
                                             const _Float16* __restrict__ hgz,
                                             const _Float16* __restrict__ hgr,
                                             float* __restrict__ out)
{
  const int tid = threadIdx.x;
  const int l = tid & 63, r = l & 15, q = l >> 4;
  const int row0 = q*4;

  if (blockIdx.x < 1024){
    const int wid = blockIdx.x * 4 + (tid >> 6);
    const int u0 = wid * 16;

    half4v I1A, I2A, IMuA, ICovA, Z1A, Z2A, ZMuA, ZCovA;
    float bI1v[4], bI2v[4], bIMu[4], bICov[4], bZ1v[4], bZ2v[4], bZMu[4], bZCov[4];
    #pragma unroll
    for (int j = 0; j < 4; ++j){
      const int k = q*4 + j;
      I1A[j]  = (_Float16)ip.p[14][r*16 + k];
      I2A[j]  = (_Float16)ip.p[16][r*16 + k];
      IMuA[j] = (r < 10) ? (_Float16)ip.p[18][r*16 + k] : (_Float16)0.f;
      ICovA[j]= (r < 10) ? (_Float16)ip.p[20][r*16 + k] : (_Float16)0.f;
      Z1A[j]  = (_Float16)ip.p[26][r*16 + k];
      Z2A[j]  = (_Float16)ip.p[28][r*16 + k];
      ZMuA[j] = (r < 10) ? (_Float16)ip.p[30][r*16 + k] : (_Float16)0.f;
      ZCovA[j]= (r < 10) ? (_Float16)ip.p[32][r*16 + k] : (_Float16)0.f;
    }
    #pragma unroll
    for (int i = 0; i < 4; ++i){
      const int row = row0 + i;
      bI1v[i] = ip.p[15][row];  bI2v[i] = ip.p[17][row];
      bIMu[i]  = (row < 10) ? ip.p[19][row] : 0.f;
      bICov[i] = (row < 10) ? ip.p[21][row] : 0.f;
      bZ1v[i] = ip.p[27][row];  bZ2v[i] = ip.p[29][row];
      bZMu[i]  = (row < 10) ? ip.p[31][row] : 0.f;
      bZCov[i] = (row < 10) ? ip.p[33][row] : 0.f;
    }

    float kl_acc = 0.f;
    for (int k = 0; k < 16; ++k){
      const int u = u0 + k;
      const int tile = u >> 9, t = u & 511;
      const size_t off = (((size_t)t*Bb + tile*16 + r) << 4) + q*4;
      const half4v hzB  = *(const half4v*)(hz  + off);
      const half4v hgzB = *(const half4v*)(hgz + off);

      float4v H1 = {bI1v[0],bI1v[1],bI1v[2],bI1v[3]};
      H1 = MFMA16(I1A, hzB, H1);
      const half4v h1B = relu_pack(H1);
      float4v H2 = {bI2v[0],bI2v[1],bI2v[2],bI2v[3]};
      H2 = MFMA16(I2A, h1B, H2);
      const half4v h2B = relu_pack(H2);
      float4v Qmu  = {bIMu[0],bIMu[1],bIMu[2],bIMu[3]};
      float4v Qpre = {bICov[0],bICov[1],bICov[2],bICov[3]};
      Qmu  = MFMA16(IMuA,  h2B, Qmu);
      Qpre = MFMA16(ICovA, h2B, Qpre);

      float4v G1 = {bZ1v[0],bZ1v[1],bZ1v[2],bZ1v[3]};
      G1 = MFMA16(Z1A, hgzB, G1);
      const half4v g1B = relu_pack(G1);
      float4v G2 = {bZ2v[0],bZ2v[1],bZ2v[2],bZ2v[3]};
      G2 = MFMA16(Z2A, g1B, G2);
      const half4v g2B = relu_pack(G2);
      float4v Pmu  = {bZMu[0],bZMu[1],bZMu[2],bZMu[3]};
      float4v Ppre = {bZCov[0],bZCov[1],bZCov[2],bZCov[3]};
      Pmu  = MFMA16(ZMuA,  g2B, Pmu);
      Ppre = MFMA16(ZCovA, g2B, Ppre);

      #pragma unroll
      for (int ii = 0; ii < 4; ++ii){
        const float qs = __expf(Qpre[ii]);
        const float dm = Qmu[ii] - Pmu[ii];
        kl_acc += (Ppre[ii] - Qpre[ii]) + (qs*qs + dm*dm)*0.5f*__expf(-2.f*Ppre[ii]) - 0.5f;
      }
    }
    #pragma unroll
    for (int m = 1; m < 64; m <<= 1) kl_acc += __shfl_xor(kl_acc, m, 64);
    if (l == 0) atomicAdd(&out[1], kl_acc * (1.f/(float)Bb));
  } else {
    const int wid = (blockIdx.x - 1024) * 4 + (tid >> 6);
    const int u0 = wid * 16;

    half4v R1A, R2A[12];
    float bR1v[4], bR2v[12][4];
    #pragma unroll
    for (int j = 0; j < 4; ++j){
      const int k = q*4 + j;
      R1A[j] = (_Float16)ip.p[38][r*16 + k];
      #pragma unroll
      for (int m = 0; m < 12; ++m)
        R2A[m][j] = (_Float16)ip.p[40][(m*16 + r)*16 + k];
    }
    #pragma unroll
    for (int i = 0; i < 4; ++i){
      const int row = row0 + i;
      bR1v[i] = ip.p[39][row];
      #pragma unroll
      for (int m = 0; m < 12; ++m) bR2v[m][i] = ip.p[41][m*16 + row];
    }

    float nll_acc = 0.f;
    for (int k = 0; k < 16; ++k){
      const int u = u0 + k;
      const int tile = u >> 9, t = u & 511;
      const half4v hgrB = *(const half4v*)(hgr + (((size_t)t*Bb + tile*16 + r) << 4) + q*4);
      const float* xrow = ip.p[0] + ((size_t)(tile*16 + r) * Tt + t) * 64;
      float4v xv[4];
      #pragma unroll
      for (int m = 0; m < 4; ++m) xv[m] = *(const float4v*)(xrow + m*16 + q*4);

      float4v R1D = {bR1v[0],bR1v[1],bR1v[2],bR1v[3]};
      R1D = MFMA16(R1A, hgrB, R1D);
      const half4v r1B = relu_pack(R1D);

      float s1 = 0.f, s2 = 0.f, s3 = 0.f, s4 = 0.f;
      #pragma unroll
      for (int m = 0; m < 4; ++m){
        float4v Dmu = {bR2v[m][0],bR2v[m][1],bR2v[m][2],bR2v[m][3]};
        float4v Ddp = {bR2v[4+m][0],bR2v[4+m][1],bR2v[4+m][2],bR2v[4+m][3]};
        float4v Dw  = {bR2v[8+m][0],bR2v[8+m][1],bR2v[8+m][2],bR2v[8+m][3]};
        Dmu = MFMA16(R2A[m],   r1B, Dmu);
        Ddp = MFMA16(R2A[4+m], r1B, Ddp);
        Dw  = MFMA16(R2A[8+m], r1B, Dw);
        #pragma unroll
        for (int ii = 0; ii < 4; ++ii){
          const float diag = __expf(Ddp[ii]) + 1e-4f;
          const float dinv = rcpf(diag);
          const float delta = xv[m][ii] - Dmu[ii];
          const float wv = Dw[ii];
          s1 += delta*delta*dinv;
          s2 += wv*wv*dinv;
          s3 += wv*dinv*delta;
          s4 += __logf(diag);
        }
      }
      s1 += __shfl_xor(s1, 16, 64); s1 += __shfl_xor(s1, 32, 64);
      s2 += __shfl_xor(s2, 16, 64); s2 += __shfl_xor(s2, 32, 64);
      s3 += __shfl_xor(s3, 16, 64); s3 += __shfl_xor(s3, 32, 64);
      s4 += __shfl_xor(s4, 16, 64); s4 += __shfl_xor(s4, 32, 64);
      const float cap = 1.f + s2;
      const float maha = s1 - s3*s3*rcpf(cap);
      const float logdet = s4 + __logf(cap);
      nll_acc += 0.5f*(64.f*LOG2PI_ + logdet + maha);
    }
    #pragma unroll
    for (int m = 1; m < 64; m <<= 1) nll_acc += __shfl_xor(nll_acc, m, 64);
    if (l == 0) atomicAdd(&out[0], nll_acc * 0.25f * (1.f/(float)Bb));
  }
}

} // namespace

extern "C" void kernel_launch(void* const* d_in, const int* in_sizes, int n_in,
                              void* d_out, int out_size, void* d_ws, size_t ws_size,
                              hipStream_t stream)
{
  InPtrs ip;
  for (int i = 0; i < 42; ++i) ip.p[i] = (const float*)d_in[i];
  float* out = (float*)d_out;

  const size_t SZ = (size_t)Tt * Bb * 16;
  _Float16* hf  = (_Float16*)d_ws;
  _Float16* hb  = hf  + SZ;
  _Float16* hz  = hb  + SZ;
  _Float16* hgz = hz  + SZ;
  _Float16* hgr = hgz + SZ;

  zero2<<<1, 64, 0, stream>>>(out);
  dim3 gb(Bb/16, 2);
  bigru<<<gb, 64, 0, stream>>>(ip, hf, hb);
  vae_fused<<<Bb/16, 64, 0, stream>>>(ip, hf, hb, hz, hgz, hgr);
  epi<<<2048, 256, 0, stream>>>(ip, hz, hgz, hgr, out);
}

// Round 4
// 1135.135 us; speedup vs baseline: 1.1687x; 1.1687x over previous
//
#include <hip/hip_runtime.h>

namespace {

typedef __attribute__((ext_vector_type(4))) _Float16 half4v;
typedef __attribute__((ext_vector_type(4))) float   float4v;
typedef unsigned int u32;

#define MFMA16(a,b,c) __builtin_amdgcn_mfma_f32_16x16x16f16((a),(b),(c),0,0,0)

constexpr int Bb = 2048;
constexpr int Tt = 512;
constexpr float LOG2PI_ = 1.8378770664093453f;

struct InPtrs { const float* p[42]; };

__device__ __forceinline__ float rcpf(float x){ return __builtin_amdgcn_rcpf(x); }
__device__ __forceinline__ float sigm(float x){ return rcpf(1.0f + __expf(-x)); }
__device__ __forceinline__ float tanh_(float x){ return 1.0f - 2.0f*rcpf(1.0f + __expf(2.0f*x)); }

// LDS-only barrier: waits lgkmcnt(0) but does NOT drain vmcnt, so global
// prefetch loads / streaming stores stay in flight across the barrier.
__device__ __forceinline__ void barrier_lds(){
  asm volatile("s_waitcnt lgkmcnt(0)" ::: "memory");
  __builtin_amdgcn_s_barrier();
  asm volatile("" ::: "memory");
}

__device__ __forceinline__ void gru_update(const float4v& Dr, const float4v& Dz,
                                           const float4v& Dn, const float4v& Dh, half4v& hB){
  #pragma unroll
  for (int i = 0; i < 4; ++i){
    const float rr = sigm(Dr[i]);
    const float zz = sigm(Dz[i]);
    const float nn = tanh_(Dn[i] + rr*Dh[i]);
    const float hp = (float)hB[i];
    hB[i] = (_Float16)(nn + zz*(hp - nn));
  }
}

__device__ __forceinline__ half4v relu_pack(const float4v& D){
  half4v o;
  #pragma unroll
  for (int i = 0; i < 4; ++i) o[i] = (_Float16)fmaxf(D[i], 0.f);
  return o;
}

// ================= Phase 1: bi-GRU, 2 producers + 1 consumer =================
// grid (128, 2) x 192 threads. Producers P0 (even steps) and P1 (odd steps)
// each compute gi = Wih@x + biases for their half of chunk c into buffer c&1;
// lgkm-only barrier; consumer runs the h recurrence for chunk c while the
// producers fill chunk c+1. Each producer has its own depth-4 x register ring.
constexpr int CH = 8;
constexpr int NCH = Tt / CH;   // 64

__global__ __launch_bounds__(192,1) void bigru(InPtrs ip, _Float16* __restrict__ hf,
                                               _Float16* __restrict__ hb, float* __restrict__ out)
{
  const int tid = threadIdx.x;
  const int w = tid / 64;
  const int l = tid & 63, r = l & 15, q = l >> 4;
  const int dir = blockIdx.y;
  const int base = blockIdx.x * 16;

  if (blockIdx.x == 0 && blockIdx.y == 0 && tid < 2) out[tid] = 0.f;

  const float* __restrict__ x   = ip.p[0];
  const float* __restrict__ Wih = dir ? ip.p[6] : ip.p[2];
  const float* __restrict__ Whh = dir ? ip.p[7] : ip.p[3];
  const float* __restrict__ bih = dir ? ip.p[8] : ip.p[4];
  const float* __restrict__ bhh = dir ? ip.p[9] : ip.p[5];
  _Float16* __restrict__ hout = dir ? hb : hf;

  __shared__ __align__(16) float giS[2][CH][64][12];   // 48 KB

  // producer state (waves 1,2)
  half4v Wi[3][4];
  float  b0[4], b1[4], b2[4];
  float4v xp[4][4];              // per-producer depth-4 ring (covers its 4 steps/chunk)
  // consumer state (wave 0)
  half4v Wh[3];
  float  bh2[4];
  half4v hB = {0,0,0,0};
  const float* xrow = x + (size_t)(base + r) * Tt * 64;
  const int p = w - 1;           // producer parity (valid when w>=1)

  if (w >= 1){
    #pragma unroll
    for (int rt = 0; rt < 3; ++rt)
      #pragma unroll
      for (int kt = 0; kt < 4; ++kt)
        #pragma unroll
        for (int j = 0; j < 4; ++j)
          Wi[rt][kt][j] = (_Float16)Wih[(rt*16 + r)*64 + kt*16 + q*4 + j];
    #pragma unroll
    for (int i = 0; i < 4; ++i){
      const int row = q*4 + i;
      b0[i] = bih[row]      + bhh[row];
      b1[i] = bih[16 + row] + bhh[16 + row];
      b2[i] = bih[32 + row];
    }
    // preload this producer's steps of chunk 0: st = sl*2 + p
    #pragma unroll
    for (int sl = 0; sl < 4; ++sl){
      const int tg = sl*2 + p;
      const int tn = dir ? Tt-1-tg : tg;
      #pragma unroll
      for (int kt = 0; kt < 4; ++kt)
        xp[sl][kt] = *(const float4v*)(xrow + (size_t)tn*64 + kt*16 + q*4);
    }
  } else {
    #pragma unroll
    for (int rt = 0; rt < 3; ++rt)
      #pragma unroll
      for (int j = 0; j < 4; ++j)
        Wh[rt][j] = (_Float16)Whh[(rt*16 + r)*16 + q*4 + j];
    #pragma unroll
    for (int i = 0; i < 4; ++i) bh2[i] = bhh[32 + q*4 + i];
  }

  for (int c = 0; c < NCH; ++c){
    if (w >= 1){
      // ---- produce this wave's 4 steps of chunk c ----
      #pragma unroll
      for (int sl = 0; sl < 4; ++sl){
        const int st = sl*2 + p;
        const int tg = c*CH + st;
        half4v xB[4];
        #pragma unroll
        for (int kt = 0; kt < 4; ++kt)
          #pragma unroll
          for (int j = 0; j < 4; ++j) xB[kt][j] = (_Float16)xp[sl][kt][j];
        const int tp = tg + CH;      // refill with same-parity step of next chunk
        if (tp < Tt){
          const int tn = dir ? Tt-1-tp : tp;
          #pragma unroll
          for (int kt = 0; kt < 4; ++kt)
            xp[sl][kt] = *(const float4v*)(xrow + (size_t)tn*64 + kt*16 + q*4);
        }
        float4v A0 = {b0[0],b0[1],b0[2],b0[3]};
        float4v A1 = {b1[0],b1[1],b1[2],b1[3]};
        float4v A2 = {b2[0],b2[1],b2[2],b2[3]};
        #pragma unroll
        for (int kt = 0; kt < 4; ++kt){
          A0 = MFMA16(Wi[0][kt], xB[kt], A0);
          A1 = MFMA16(Wi[1][kt], xB[kt], A1);
          A2 = MFMA16(Wi[2][kt], xB[kt], A2);
        }
        float* o = &giS[c&1][st][l][0];
        *(float4v*)(o + 0) = A0;
        *(float4v*)(o + 4) = A1;
        *(float4v*)(o + 8) = A2;
      }
    }
    barrier_lds();               // block-uniform, lgkm-only
    if (w == 0){
      // ---- consume chunk c (overlaps production of chunk c+1) ----
      #pragma unroll
      for (int st = 0; st < CH; ++st){
        const int tg = c*CH + st;
        const int t = dir ? Tt-1-tg : tg;
        const float* gi = &giS[c&1][st][l][0];
        float4v A0 = *(const float4v*)(gi + 0);
        float4v A1 = *(const float4v*)(gi + 4);
        float4v A2 = *(const float4v*)(gi + 8);
        float4v Dh = {bh2[0],bh2[1],bh2[2],bh2[3]};
        A0 = MFMA16(Wh[0], hB, A0);
        A1 = MFMA16(Wh[1], hB, A1);
        Dh = MFMA16(Wh[2], hB, Dh);
        gru_update(A0, A1, A2, Dh, hB);
        *(half4v*)(hout + (((size_t)t*Bb + base + r) << 4) + q*4) = hB;
      }
    }
  }
}

// ================= Phase 3a: sequential VAE recurrences, 2 steps per barrier ==========
// 3-wave skewed pipeline. Wave A (step i): infz GRU + inf head + z, publishes z
// into an 8-slot LDS ring (slot = step&7). Wave B (step i-2): genz GRU.
// Wave C (step i-4): genr GRU. One lgkm-only barrier per TWO steps; the z->z
// cycle stays inside wave A so throughput is unchanged while sync cost halves.
// Skew algebra: B at step s reads z(s-1) (published >=1 barrier earlier);
// C at step u reads z(u) (published >=2 barriers earlier); slot reuse distance
// is 8 steps = 4 barriers, so no WAR hazard.
__global__ __launch_bounds__(192,1) void vae_seq(InPtrs ip, const _Float16* __restrict__ hf,
                                                 const _Float16* __restrict__ hb,
                                                 _Float16* __restrict__ hz,
                                                 _Float16* __restrict__ hgz,
                                                 _Float16* __restrict__ hgr)
{
  const int tid = threadIdx.x;
  const int w = tid / 64;
  const int l = tid & 63, r = l & 15, q = l >> 4;
  const int base = blockIdx.x * 16;
  const int row0 = q*4;

  __shared__ u32 zS[8][2][64];
  for (int i = tid; i < 8*2*64; i += 192) ((u32*)zS)[i] = 0u;
  barrier_lds();

  // ---- per-wave persistent state ----
  // wave A
  half4v WizA[3][3], WhzA[3], I1A, I2A, IMuA, ICovA;
  float bz0[4], bz1[4], bzn[4], bzh[4], bI1v[4], bI2v[4], bIMu[4], bICov[4];
  half4v hzB = {0,0,0,0}, zB = {0,0,0,0};
  half4v hrR[4], hlR[4];     // depth-4 prefetch ring
  float4v eR[4];
  // wave B
  half4v WgzA[3], WhgzA[3];
  float bg0[4], bg1[4], bgn[4], bgh[4];
  half4v hgzB = {0,0,0,0};
  // wave C
  half4v WgrA[3], WhgrA[3];
  float br0[4], br1[4], brn[4], brh[4];
  half4v hgrB = {0,0,0,0};

  const float* erow = ip.p[1] + (size_t)(base + r) * Tt * 10;

  if (w == 0){
    #pragma unroll
    for (int rt = 0; rt < 3; ++rt)
      #pragma unroll
      for (int kt = 0; kt < 3; ++kt)
        #pragma unroll
        for (int j = 0; j < 4; ++j){
          const int k = kt*16 + q*4 + j;
          int c;
          if (kt == 0) c = (k < 10) ? k : -1;
          else if (kt == 1) c = 10 + (k - 16);
          else c = 26 + (k - 32);
          WizA[rt][kt][j] = (c >= 0) ? (_Float16)ip.p[10][(rt*16 + r)*42 + c] : (_Float16)0.f;
        }
    #pragma unroll
    for (int rt = 0; rt < 3; ++rt)
      #pragma unroll
      for (int j = 0; j < 4; ++j)
        WhzA[rt][j] = (_Float16)ip.p[11][(rt*16 + r)*16 + q*4 + j];
    #pragma unroll
    for (int j = 0; j < 4; ++j){
      const int k = q*4 + j;
      I1A[j]  = (_Float16)ip.p[14][r*16 + k];
      I2A[j]  = (_Float16)ip.p[16][r*16 + k];
      IMuA[j] = (r < 10) ? (_Float16)ip.p[18][r*16 + k] : (_Float16)0.f;
      ICovA[j]= (r < 10) ? (_Float16)ip.p[20][r*16 + k] : (_Float16)0.f;
    }
    #pragma unroll
    for (int i = 0; i < 4; ++i){
      const int row = row0 + i;
      bz0[i] = ip.p[12][row]    + ip.p[13][row];
      bz1[i] = ip.p[12][16+row] + ip.p[13][16+row];
      bzn[i] = ip.p[12][32+row];
      bzh[i] = ip.p[13][32+row];
      bI1v[i] = ip.p[15][row];  bI2v[i] = ip.p[17][row];
      bIMu[i]  = (row < 10) ? ip.p[19][row] : 0.f;
      bICov[i] = (row < 10) ? ip.p[21][row] : 0.f;
    }
    // preload ring slots for steps 0..3
    #pragma unroll
    for (int s = 0; s < 4; ++s){
      if (s >= 1) hrR[s] = *(const half4v*)(hf + (((size_t)(s-1)*Bb + base + r) << 4) + q*4);
      else { half4v z0 = {0,0,0,0}; hrR[s] = z0; }
      hlR[s] = *(const half4v*)(hb + (((size_t)(s+1)*Bb + base + r) << 4) + q*4);
      float4v et;
      #pragma unroll
      for (int ii = 0; ii < 4; ++ii) et[ii] = (row0 + ii < 10) ? erow[s*10 + row0 + ii] : 0.f;
      eR[s] = et;
    }
  } else if (w == 1){
    #pragma unroll
    for (int rt = 0; rt < 3; ++rt)
      #pragma unroll
      for (int j = 0; j < 4; ++j){
        const int k = q*4 + j;
        WgzA[rt][j]  = (k < 10) ? (_Float16)ip.p[22][(rt*16 + r)*10 + k] : (_Float16)0.f;
        WhgzA[rt][j] = (_Float16)ip.p[23][(rt*16 + r)*16 + k];
      }
    #pragma unroll
    for (int i = 0; i < 4; ++i){
      const int row = row0 + i;
      bg0[i] = ip.p[24][row]    + ip.p[25][row];
      bg1[i] = ip.p[24][16+row] + ip.p[25][16+row];
      bgn[i] = ip.p[24][32+row];
      bgh[i] = ip.p[25][32+row];
    }
  } else {
    #pragma unroll
    for (int rt = 0; rt < 3; ++rt)
      #pragma unroll
      for (int j = 0; j < 4; ++j){
        const int k = q*4 + j;
        WgrA[rt][j]  = (k < 10) ? (_Float16)ip.p[34][(rt*16 + r)*10 + k] : (_Float16)0.f;
        WhgrA[rt][j] = (_Float16)ip.p[35][(rt*16 + r)*16 + k];
      }
    #pragma unroll
    for (int i = 0; i < 4; ++i){
      const int row = row0 + i;
      br0[i] = ip.p[36][row]    + ip.p[37][row];
      br1[i] = ip.p[36][16+row] + ip.p[37][16+row];
      brn[i] = ip.p[36][32+row];
      brh[i] = ip.p[37][32+row];
    }
  }

  // ---- pipeline loop: barrier after every 2 steps (k==1, k==3) ----
  for (int ib = 0; ib < Tt + 4; ib += 4){
    #pragma unroll
    for (int k = 0; k < 4; ++k){
      const int i = ib + k;
      if (w == 0){
        if (i < Tt){
          const half4v hrB = hrR[k], hlB = hlR[k];
          const float4v ev = eR[k];
          // prefetch step i+4 into the just-freed slot (static index k)
          const int f = i + 4;
          if (f < Tt){
            hrR[k] = *(const half4v*)(hf + (((size_t)(f-1)*Bb + base + r) << 4) + q*4);
            if (f <= Tt-2) hlR[k] = *(const half4v*)(hb + (((size_t)(f+1)*Bb + base + r) << 4) + q*4);
            else { half4v z0 = {0,0,0,0}; hlR[k] = z0; }
            float4v et;
            #pragma unroll
            for (int ii = 0; ii < 4; ++ii) et[ii] = (row0 + ii < 10) ? erow[f*10 + row0 + ii] : 0.f;
            eR[k] = et;
          }
          // accumulate: hr, hl (ready) -> hz -> z last
          float4v Dr = {bz0[0],bz0[1],bz0[2],bz0[3]};
          float4v Dz = {bz1[0],bz1[1],bz1[2],bz1[3]};
          float4v Dn = {bzn[0],bzn[1],bzn[2],bzn[3]};
          float4v Dh = {bzh[0],bzh[1],bzh[2],bzh[3]};
          Dr = MFMA16(WizA[0][1], hrB, Dr); Dr = MFMA16(WizA[0][2], hlB, Dr);
          Dz = MFMA16(WizA[1][1], hrB, Dz); Dz = MFMA16(WizA[1][2], hlB, Dz);
          Dn = MFMA16(WizA[2][1], hrB, Dn); Dn = MFMA16(WizA[2][2], hlB, Dn);
          Dr = MFMA16(WhzA[0], hzB, Dr);
          Dz = MFMA16(WhzA[1], hzB, Dz);
          Dh = MFMA16(WhzA[2], hzB, Dh);
          Dr = MFMA16(WizA[0][0], zB, Dr);
          Dz = MFMA16(WizA[1][0], zB, Dz);
          Dn = MFMA16(WizA[2][0], zB, Dn);
          gru_update(Dr, Dz, Dn, Dh, hzB);
          *(half4v*)(hz + (((size_t)i*Bb + base + r) << 4) + q*4) = hzB;

          float4v H1 = {bI1v[0],bI1v[1],bI1v[2],bI1v[3]};
          H1 = MFMA16(I1A, hzB, H1);
          const half4v h1B = relu_pack(H1);
          float4v H2 = {bI2v[0],bI2v[1],bI2v[2],bI2v[3]};
          H2 = MFMA16(I2A, h1B, H2);
          const half4v h2B = relu_pack(H2);
          float4v Qmu  = {bIMu[0],bIMu[1],bIMu[2],bIMu[3]};
          float4v Qpre = {bICov[0],bICov[1],bICov[2],bICov[3]};
          Qmu  = MFMA16(IMuA,  h2B, Qmu);
          Qpre = MFMA16(ICovA, h2B, Qpre);

          #pragma unroll
          for (int ii = 0; ii < 4; ++ii){
            const float qs = __expf(Qpre[ii]);
            zB[ii] = (_Float16)(Qmu[ii] + qs*ev[ii]);
          }
          union { half4v h; u32 u[2]; } zc; zc.h = zB;
          const int slot = i & 7;
          zS[slot][0][l] = zc.u[0];
          zS[slot][1][l] = zc.u[1];
        }
      } else if (w == 1){
        if (i >= 2 && i < Tt + 2){
          const int s = i - 2;
          union { half4v h; u32 u[2]; } zc;
          const int sp = (s - 1) & 7;
          zc.u[0] = zS[sp][0][l]; zc.u[1] = zS[sp][1][l];
          const half4v zPrev = zc.h;

          float4v Er = {bg0[0],bg0[1],bg0[2],bg0[3]};
          float4v Ez = {bg1[0],bg1[1],bg1[2],bg1[3]};
          float4v En = {bgn[0],bgn[1],bgn[2],bgn[3]};
          float4v Eh = {bgh[0],bgh[1],bgh[2],bgh[3]};
          Er = MFMA16(WgzA[0], zPrev, Er); Er = MFMA16(WhgzA[0], hgzB, Er);
          Ez = MFMA16(WgzA[1], zPrev, Ez); Ez = MFMA16(WhgzA[1], hgzB, Ez);
          En = MFMA16(WgzA[2], zPrev, En);
          Eh = MFMA16(WhgzA[2], hgzB, Eh);
          gru_update(Er, Ez, En, Eh, hgzB);
          *(half4v*)(hgz + (((size_t)s*Bb + base + r) << 4) + q*4) = hgzB;
        }
      } else {
        if (i >= 4 && i < Tt + 4){
          const int u = i - 4;
          union { half4v h; u32 uu[2]; } zc;
          const int su = u & 7;
          zc.uu[0] = zS[su][0][l]; zc.uu[1] = zS[su][1][l];
          const half4v zU = zc.h;

          float4v Fr = {br0[0],br0[1],br0[2],br0[3]};
          float4v Fz = {br1[0],br1[1],br1[2],br1[3]};
          float4v Fn = {brn[0],brn[1],brn[2],brn[3]};
          float4v Fh = {brh[0],brh[1],brh[2],brh[3]};
          Fr = MFMA16(WgrA[0], zU, Fr); Fr = MFMA16(WhgrA[0], hgrB, Fr);
          Fz = MFMA16(WgrA[1], zU, Fz); Fz = MFMA16(WhgrA[1], hgrB, Fz);
          Fn = MFMA16(WgrA[2], zU, Fn);
          Fh = MFMA16(WhgrA[2], hgrB, Fh);
          gru_update(Fr, Fz, Fn, Fh, hgrB);
          *(half4v*)(hgr + (((size_t)u*Bb + base + r) << 4) + q*4) = hgrB;
        }
      }
      if (k & 1) barrier_lds();   // barrier after steps {1,3} of the body
    }
  }
}

// ================= Phase 3b: merged parallel epilogue =================
// Blocks [0,2048): KL; blocks [2048,4096): NLL. 8 units per wave.
__global__ __launch_bounds__(256,2) void epi(InPtrs ip, const _Float16* __restrict__ hz,
                                             const _Float16* __restrict__ hgz,
                                             const _Float16* __restrict__ hgr,
                                             float* __restrict__ out)
{
  const int tid = threadIdx.x;
  const int l = tid & 63, r = l & 15, q = l >> 4;
  const int row0 = q*4;

  if (blockIdx.x < 2048){
    const int wid = blockIdx.x * 4 + (tid >> 6);   // 8192 waves
    const int u0 = wid * 8;

    half4v I1A, I2A, IMuA, ICovA, Z1A, Z2A, ZMuA, ZCovA;
    float bI1v[4], bI2v[4], bIMu[4], bICov[4], bZ1v[4], bZ2v[4], bZMu[4], bZCov[4];
    #pragma unroll
    for (int j = 0; j < 4; ++j){
      const int k = q*4 + j;
      I1A[j]  = (_Float16)ip.p[14][r*16 + k];
      I2A[j]  = (_Float16)ip.p[16][r*16 + k];
      IMuA[j] = (r < 10) ? (_Float16)ip.p[18][r*16 + k] : (_Float16)0.f;
      ICovA[j]= (r < 10) ? (_Float16)ip.p[20][r*16 + k] : (_Float16)0.f;
      Z1A[j]  = (_Float16)ip.p[26][r*16 + k];
      Z2A[j]  = (_Float16)ip.p[28][r*16 + k];
      ZMuA[j] = (r < 10) ? (_Float16)ip.p[30][r*16 + k] : (_Float16)0.f;
      ZCovA[j]= (r < 10) ? (_Float16)ip.p[32][r*16 + k] : (_Float16)0.f;
    }
    #pragma unroll
    for (int i = 0; i < 4; ++i){
      const int row = row0 + i;
      bI1v[i] = ip.p[15][row];  bI2v[i] = ip.p[17][row];
      bIMu[i]  = (row < 10) ? ip.p[19][row] : 0.f;
      bICov[i] = (row < 10) ? ip.p[21][row] : 0.f;
      bZ1v[i] = ip.p[27][row];  bZ2v[i] = ip.p[29][row];
      bZMu[i]  = (row < 10) ? ip.p[31][row] : 0.f;
      bZCov[i] = (row < 10) ? ip.p[33][row] : 0.f;
    }

    float kl_acc = 0.f;
    for (int k = 0; k < 8; ++k){
      const int u = u0 + k;
      const int tile = u >> 9, t = u & 511;
      const size_t off = (((size_t)t*Bb + tile*16 + r) << 4) + q*4;
      const half4v hzB  = *(const half4v*)(hz  + off);
      const half4v hgzB = *(const half4v*)(hgz + off);

      float4v H1 = {bI1v[0],bI1v[1],bI1v[2],bI1v[3]};
      H1 = MFMA16(I1A, hzB, H1);
      const half4v h1B = relu_pack(H1);
      float4v H2 = {bI2v[0],bI2v[1],bI2v[2],bI2v[3]};
      H2 = MFMA16(I2A, h1B, H2);
      const half4v h2B = relu_pack(H2);
      float4v Qmu  = {bIMu[0],bIMu[1],bIMu[2],bIMu[3]};
      float4v Qpre = {bICov[0],bICov[1],bICov[2],bICov[3]};
      Qmu  = MFMA16(IMuA,  h2B, Qmu);
      Qpre = MFMA16(ICovA, h2B, Qpre);

      float4v G1 = {bZ1v[0],bZ1v[1],bZ1v[2],bZ1v[3]};
      G1 = MFMA16(Z1A, hgzB, G1);
      const half4v g1B = relu_pack(G1);
      float4v G2 = {bZ2v[0],bZ2v[1],bZ2v[2],bZ2v[3]};
      G2 = MFMA16(Z2A, g1B, G2);
      const half4v g2B = relu_pack(G2);
      float4v Pmu  = {bZMu[0],bZMu[1],bZMu[2],bZMu[3]};
      float4v Ppre = {bZCov[0],bZCov[1],bZCov[2],bZCov[3]};
      Pmu  = MFMA16(ZMuA,  g2B, Pmu);
      Ppre = MFMA16(ZCovA, g2B, Ppre);

      #pragma unroll
      for (int ii = 0; ii < 4; ++ii){
        const float qs = __expf(Qpre[ii]);
        const float dm = Qmu[ii] - Pmu[ii];
        kl_acc += (Ppre[ii] - Qpre[ii]) + (qs*qs + dm*dm)*0.5f*__expf(-2.f*Ppre[ii]) - 0.5f;
      }
    }
    #pragma unroll
    for (int m = 1; m < 64; m <<= 1) kl_acc += __shfl_xor(kl_acc, m, 64);
    if (l == 0) atomicAdd(&out[1], kl_acc * (1.f/(float)Bb));
  } else {
    const int wid = (blockIdx.x - 2048) * 4 + (tid >> 6);   // 8192 waves
    const int u0 = wid * 8;

    half4v R1A, R2A[12];
    float bR1v[4], bR2v[12][4];
    #pragma unroll
    for (int j = 0; j < 4; ++j){
      const int k = q*4 + j;
      R1A[j] = (_Float16)ip.p[38][r*16 + k];
      #pragma unroll
      for (int m = 0; m < 12; ++m)
        R2A[m][j] = (_Float16)ip.p[40][(m*16 + r)*16 + k];
    }
    #pragma unroll
    for (int i = 0; i < 4; ++i){
      const int row = row0 + i;
      bR1v[i] = ip.p[39][row];
      #pragma unroll
      for (int m = 0; m < 12; ++m) bR2v[m][i] = ip.p[41][m*16 + row];
    }

    float nll_acc = 0.f;
    for (int k = 0; k < 8; ++k){
      const int u = u0 + k;
      const int tile = u >> 9, t = u & 511;
      const half4v hgrB = *(const half4v*)(hgr + (((size_t)t*Bb + tile*16 + r) << 4) + q*4);
      const float* xrow = ip.p[0] + ((size_t)(tile*16 + r) * Tt + t) * 64;
      float4v xv[4];
      #pragma unroll
      for (int m = 0; m < 4; ++m) xv[m] = *(const float4v*)(xrow + m*16 + q*4);

      float4v R1D = {bR1v[0],bR1v[1],bR1v[2],bR1v[3]};
      R1D = MFMA16(R1A, hgrB, R1D);
      const half4v r1B = relu_pack(R1D);

      float s1 = 0.f, s2 = 0.f, s3 = 0.f, s4 = 0.f;
      #pragma unroll
      for (int m = 0; m < 4; ++m){
        float4v Dmu = {bR2v[m][0],bR2v[m][1],bR2v[m][2],bR2v[m][3]};
        float4v Ddp = {bR2v[4+m][0],bR2v[4+m][1],bR2v[4+m][2],bR2v[4+m][3]};
        float4v Dw  = {bR2v[8+m][0],bR2v[8+m][1],bR2v[8+m][2],bR2v[8+m][3]};
        Dmu = MFMA16(R2A[m],   r1B, Dmu);
        Ddp = MFMA16(R2A[4+m], r1B, Ddp);
        Dw  = MFMA16(R2A[8+m], r1B, Dw);
        #pragma unroll
        for (int ii = 0; ii < 4; ++ii){
          const float diag = __expf(Ddp[ii]) + 1e-4f;
          const float dinv = rcpf(diag);
          const float delta = xv[m][ii] - Dmu[ii];
          const float wv = Dw[ii];
          s1 += delta*delta*dinv;
          s2 += wv*wv*dinv;
          s3 += wv*dinv*delta;
          s4 += __logf(diag);
        }
      }
      s1 += __shfl_xor(s1, 16, 64); s1 += __shfl_xor(s1, 32, 64);
      s2 += __shfl_xor(s2, 16, 64); s2 += __shfl_xor(s2, 32, 64);
      s3 += __shfl_xor(s3, 16, 64); s3 += __shfl_xor(s3, 32, 64);
      s4 += __shfl_xor(s4, 16, 64); s4 += __shfl_xor(s4, 32, 64);
      const float cap = 1.f + s2;
      const float maha = s1 - s3*s3*rcpf(cap);
      const float logdet = s4 + __logf(cap);
      nll_acc += 0.5f*(64.f*LOG2PI_ + logdet + maha);
    }
    #pragma unroll
    for (int m = 1; m < 64; m <<= 1) nll_acc += __shfl_xor(nll_acc, m, 64);
    if (l == 0) atomicAdd(&out[0], nll_acc * 0.25f * (1.f/(float)Bb));
  }
}

} // namespace

extern "C" void kernel_launch(void* const* d_in, const int* in_sizes, int n_in,
                              void* d_out, int out_size, void* d_ws, size_t ws_size,
                              hipStream_t stream)
{
  InPtrs ip;
  for (int i = 0; i < 42; ++i) ip.p[i] = (const float*)d_in[i];
  float* out = (float*)d_out;

  const size_t SZ = (size_t)Tt * Bb * 16;
  _Float16* hf  = (_Float16*)d_ws;
  _Float16* hb  = hf  + SZ;
  _Float16* hz  = hb  + SZ;
  _Float16* hgz = hz  + SZ;
  _Float16* hgr = hgz + SZ;

  dim3 gb(Bb/16, 2);
  bigru<<<gb, 192, 0, stream>>>(ip, hf, hb, out);
  vae_seq<<<Bb/16, 192, 0, stream>>>(ip, hf, hb, hz, hgz, hgr);
  epi<<<4096, 256, 0, stream>>>(ip, hz, hgz, hgr, out);
}

// Round 5
// 996.859 us; speedup vs baseline: 1.3308x; 1.1387x over previous
//
#include <hip/hip_runtime.h>

namespace {

typedef __attribute__((ext_vector_type(4))) _Float16 half4v;
typedef __attribute__((ext_vector_type(4))) float   float4v;
typedef unsigned int u32;

#define MFMA16(a,b,c) __builtin_amdgcn_mfma_f32_16x16x16f16((a),(b),(c),0,0,0)

constexpr int Bb = 2048;
constexpr int Tt = 512;
constexpr float LOG2PI_ = 1.8378770664093453f;

struct InPtrs { const float* p[42]; };

__device__ __forceinline__ float rcpf(float x){ return __builtin_amdgcn_rcpf(x); }
__device__ __forceinline__ float sigm(float x){ return rcpf(1.0f + __expf(-x)); }
__device__ __forceinline__ float tanh_(float x){ return 1.0f - 2.0f*rcpf(1.0f + __expf(2.0f*x)); }

// LDS-only barrier: waits lgkmcnt(0) but does NOT drain vmcnt, so global
// prefetch loads / streaming stores stay in flight across the barrier.
__device__ __forceinline__ void barrier_lds(){
  asm volatile("s_waitcnt lgkmcnt(0)" ::: "memory");
  __builtin_amdgcn_s_barrier();
  asm volatile("" ::: "memory");
}

__device__ __forceinline__ void gru_update(const float4v& Dr, const float4v& Dz,
                                           const float4v& Dn, const float4v& Dh, half4v& hB){
  #pragma unroll
  for (int i = 0; i < 4; ++i){
    const float rr = sigm(Dr[i]);
    const float zz = sigm(Dz[i]);
    const float nn = tanh_(Dn[i] + rr*Dh[i]);
    const float hp = (float)hB[i];
    hB[i] = (_Float16)(nn + zz*(hp - nn));
  }
}

__device__ __forceinline__ half4v relu_pack(const float4v& D){
  half4v o;
  #pragma unroll
  for (int i = 0; i < 4; ++i) o[i] = (_Float16)fmaxf(D[i], 0.f);
  return o;
}

// ================= Phase 1: bi-GRU, producer/consumer (best-measured R2 form) =========
constexpr int CH = 8;
constexpr int NCH = Tt / CH;   // 64

__global__ __launch_bounds__(128,1) void bigru(InPtrs ip, _Float16* __restrict__ hf,
                                               _Float16* __restrict__ hb)
{
  const int tid = threadIdx.x;
  const int w = tid >> 6;
  const int l = tid & 63, r = l & 15, q = l >> 4;
  const int dir = blockIdx.y;
  const int base = blockIdx.x * 16;

  const float* __restrict__ x   = ip.p[0];
  const float* __restrict__ Wih = dir ? ip.p[6] : ip.p[2];
  const float* __restrict__ Whh = dir ? ip.p[7] : ip.p[3];
  const float* __restrict__ bih = dir ? ip.p[8] : ip.p[4];
  const float* __restrict__ bhh = dir ? ip.p[9] : ip.p[5];
  _Float16* __restrict__ hout = dir ? hb : hf;

  __shared__ __align__(16) float giS[2][CH][64][12];   // 48 KB

  half4v Wi[3][4];            // producer
  float  b0[4], b1[4], b2[4];
  float4v xp[CH][4];          // 8-step prefetch ring
  half4v Wh[3];               // consumer
  float  bh2[4];
  half4v hB = {0,0,0,0};
  const float* xrow = x + (size_t)(base + r) * Tt * 64;

  if (w == 1){
    #pragma unroll
    for (int rt = 0; rt < 3; ++rt)
      #pragma unroll
      for (int kt = 0; kt < 4; ++kt)
        #pragma unroll
        for (int j = 0; j < 4; ++j)
          Wi[rt][kt][j] = (_Float16)Wih[(rt*16 + r)*64 + kt*16 + q*4 + j];
    #pragma unroll
    for (int i = 0; i < 4; ++i){
      const int row = q*4 + i;
      b0[i] = bih[row]      + bhh[row];
      b1[i] = bih[16 + row] + bhh[16 + row];
      b2[i] = bih[32 + row];
    }
    #pragma unroll
    for (int s = 0; s < CH; ++s){
      const int tn = dir ? Tt-1-s : s;
      #pragma unroll
      for (int kt = 0; kt < 4; ++kt)
        xp[s][kt] = *(const float4v*)(xrow + (size_t)tn*64 + kt*16 + q*4);
    }
  } else {
    #pragma unroll
    for (int rt = 0; rt < 3; ++rt)
      #pragma unroll
      for (int j = 0; j < 4; ++j)
        Wh[rt][j] = (_Float16)Whh[(rt*16 + r)*16 + q*4 + j];
    #pragma unroll
    for (int i = 0; i < 4; ++i) bh2[i] = bhh[32 + q*4 + i];
  }

  for (int c = 0; c < NCH; ++c){
    if (w == 1){
      #pragma unroll
      for (int st = 0; st < CH; ++st){
        const int tg = c*CH + st;
        half4v xB[4];
        #pragma unroll
        for (int kt = 0; kt < 4; ++kt)
          #pragma unroll
          for (int j = 0; j < 4; ++j) xB[kt][j] = (_Float16)xp[st][kt][j];
        const int tp = tg + CH;
        if (tp < Tt){
          const int tn = dir ? Tt-1-tp : tp;
          #pragma unroll
          for (int kt = 0; kt < 4; ++kt)
            xp[st][kt] = *(const float4v*)(xrow + (size_t)tn*64 + kt*16 + q*4);
        }
        float4v A0 = {b0[0],b0[1],b0[2],b0[3]};
        float4v A1 = {b1[0],b1[1],b1[2],b1[3]};
        float4v A2 = {b2[0],b2[1],b2[2],b2[3]};
        #pragma unroll
        for (int kt = 0; kt < 4; ++kt){
          A0 = MFMA16(Wi[0][kt], xB[kt], A0);
          A1 = MFMA16(Wi[1][kt], xB[kt], A1);
          A2 = MFMA16(Wi[2][kt], xB[kt], A2);
        }
        float* o = &giS[c&1][st][l][0];
        *(float4v*)(o + 0) = A0;
        *(float4v*)(o + 4) = A1;
        *(float4v*)(o + 8) = A2;
      }
    }
    barrier_lds();
    if (w == 0){
      #pragma unroll
      for (int st = 0; st < CH; ++st){
        const int tg = c*CH + st;
        const int t = dir ? Tt-1-tg : tg;
        const float* gi = &giS[c&1][st][l][0];
        float4v A0 = *(const float4v*)(gi + 0);
        float4v A1 = *(const float4v*)(gi + 4);
        float4v A2 = *(const float4v*)(gi + 8);
        float4v Dh = {bh2[0],bh2[1],bh2[2],bh2[3]};
        A0 = MFMA16(Wh[0], hB, A0);
        A1 = MFMA16(Wh[1], hB, A1);
        Dh = MFMA16(Wh[2], hB, Dh);
        gru_update(A0, A1, A2, Dh, hB);
        *(half4v*)(hout + (((size_t)t*Bb + base + r) << 4) + q*4) = hB;
      }
    }
  }
}

// ================= Phase 3a: sequential VAE recurrences (R4 form) =================
__global__ __launch_bounds__(192,1) void vae_seq(InPtrs ip, const _Float16* __restrict__ hf,
                                                 const _Float16* __restrict__ hb,
                                                 _Float16* __restrict__ hz,
                                                 _Float16* __restrict__ hgz,
                                                 _Float16* __restrict__ hgr)
{
  const int tid = threadIdx.x;
  const int w = tid / 64;
  const int l = tid & 63, r = l & 15, q = l >> 4;
  const int base = blockIdx.x * 16;
  const int row0 = q*4;

  __shared__ u32 zS[8][2][64];
  for (int i = tid; i < 8*2*64; i += 192) ((u32*)zS)[i] = 0u;
  barrier_lds();

  // wave A
  half4v WizA[3][3], WhzA[3], I1A, I2A, IMuA, ICovA;
  float bz0[4], bz1[4], bzn[4], bzh[4], bI1v[4], bI2v[4], bIMu[4], bICov[4];
  half4v hzB = {0,0,0,0}, zB = {0,0,0,0};
  half4v hrR[4], hlR[4];
  float4v eR[4];
  // wave B
  half4v WgzA[3], WhgzA[3];
  float bg0[4], bg1[4], bgn[4], bgh[4];
  half4v hgzB = {0,0,0,0};
  // wave C
  half4v WgrA[3], WhgrA[3];
  float br0[4], br1[4], brn[4], brh[4];
  half4v hgrB = {0,0,0,0};

  const float* erow = ip.p[1] + (size_t)(base + r) * Tt * 10;

  if (w == 0){
    #pragma unroll
    for (int rt = 0; rt < 3; ++rt)
      #pragma unroll
      for (int kt = 0; kt < 3; ++kt)
        #pragma unroll
        for (int j = 0; j < 4; ++j){
          const int k = kt*16 + q*4 + j;
          int c;
          if (kt == 0) c = (k < 10) ? k : -1;
          else if (kt == 1) c = 10 + (k - 16);
          else c = 26 + (k - 32);
          WizA[rt][kt][j] = (c >= 0) ? (_Float16)ip.p[10][(rt*16 + r)*42 + c] : (_Float16)0.f;
        }
    #pragma unroll
    for (int rt = 0; rt < 3; ++rt)
      #pragma unroll
      for (int j = 0; j < 4; ++j)
        WhzA[rt][j] = (_Float16)ip.p[11][(rt*16 + r)*16 + q*4 + j];
    #pragma unroll
    for (int j = 0; j < 4; ++j){
      const int k = q*4 + j;
      I1A[j]  = (_Float16)ip.p[14][r*16 + k];
      I2A[j]  = (_Float16)ip.p[16][r*16 + k];
      IMuA[j] = (r < 10) ? (_Float16)ip.p[18][r*16 + k] : (_Float16)0.f;
      ICovA[j]= (r < 10) ? (_Float16)ip.p[20][r*16 + k] : (_Float16)0.f;
    }
    #pragma unroll
    for (int i = 0; i < 4; ++i){
      const int row = row0 + i;
      bz0[i] = ip.p[12][row]    + ip.p[13][row];
      bz1[i] = ip.p[12][16+row] + ip.p[13][16+row];
      bzn[i] = ip.p[12][32+row];
      bzh[i] = ip.p[13][32+row];
      bI1v[i] = ip.p[15][row];  bI2v[i] = ip.p[17][row];
      bIMu[i]  = (row < 10) ? ip.p[19][row] : 0.f;
      bICov[i] = (row < 10) ? ip.p[21][row] : 0.f;
    }
    #pragma unroll
    for (int s = 0; s < 4; ++s){
      if (s >= 1) hrR[s] = *(const half4v*)(hf + (((size_t)(s-1)*Bb + base + r) << 4) + q*4);
      else { half4v z0 = {0,0,0,0}; hrR[s] = z0; }
      hlR[s] = *(const half4v*)(hb + (((size_t)(s+1)*Bb + base + r) << 4) + q*4);
      float4v et;
      #pragma unroll
      for (int ii = 0; ii < 4; ++ii) et[ii] = (row0 + ii < 10) ? erow[s*10 + row0 + ii] : 0.f;
      eR[s] = et;
    }
  } else if (w == 1){
    #pragma unroll
    for (int rt = 0; rt < 3; ++rt)
      #pragma unroll
      for (int j = 0; j < 4; ++j){
        const int k = q*4 + j;
        WgzA[rt][j]  = (k < 10) ? (_Float16)ip.p[22][(rt*16 + r)*10 + k] : (_Float16)0.f;
        WhgzA[rt][j] = (_Float16)ip.p[23][(rt*16 + r)*16 + k];
      }
    #pragma unroll
    for (int i = 0; i < 4; ++i){
      const int row = row0 + i;
      bg0[i] = ip.p[24][row]    + ip.p[25][row];
      bg1[i] = ip.p[24][16+row] + ip.p[25][16+row];
      bgn[i] = ip.p[24][32+row];
      bgh[i] = ip.p[25][32+row];
    }
  } else {
    #pragma unroll
    for (int rt = 0; rt < 3; ++rt)
      #pragma unroll
      for (int j = 0; j < 4; ++j){
        const int k = q*4 + j;
        WgrA[rt][j]  = (k < 10) ? (_Float16)ip.p[34][(rt*16 + r)*10 + k] : (_Float16)0.f;
        WhgrA[rt][j] = (_Float16)ip.p[35][(rt*16 + r)*16 + k];
      }
    #pragma unroll
    for (int i = 0; i < 4; ++i){
      const int row = row0 + i;
      br0[i] = ip.p[36][row]    + ip.p[37][row];
      br1[i] = ip.p[36][16+row] + ip.p[37][16+row];
      brn[i] = ip.p[36][32+row];
      brh[i] = ip.p[37][32+row];
    }
  }

  for (int ib = 0; ib < Tt + 4; ib += 4){
    #pragma unroll
    for (int k = 0; k < 4; ++k){
      const int i = ib + k;
      if (w == 0){
        if (i < Tt){
          const half4v hrB = hrR[k], hlB = hlR[k];
          const float4v ev = eR[k];
          const int f = i + 4;
          if (f < Tt){
            hrR[k] = *(const half4v*)(hf + (((size_t)(f-1)*Bb + base + r) << 4) + q*4);
            if (f <= Tt-2) hlR[k] = *(const half4v*)(hb + (((size_t)(f+1)*Bb + base + r) << 4) + q*4);
            else { half4v z0 = {0,0,0,0}; hlR[k] = z0; }
            float4v et;
            #pragma unroll
            for (int ii = 0; ii < 4; ++ii) et[ii] = (row0 + ii < 10) ? erow[f*10 + row0 + ii] : 0.f;
            eR[k] = et;
          }
          float4v Dr = {bz0[0],bz0[1],bz0[2],bz0[3]};
          float4v Dz = {bz1[0],bz1[1],bz1[2],bz1[3]};
          float4v Dn = {bzn[0],bzn[1],bzn[2],bzn[3]};
          float4v Dh = {bzh[0],bzh[1],bzh[2],bzh[3]};
          Dr = MFMA16(WizA[0][1], hrB, Dr); Dr = MFMA16(WizA[0][2], hlB, Dr);
          Dz = MFMA16(WizA[1][1], hrB, Dz); Dz = MFMA16(WizA[1][2], hlB, Dz);
          Dn = MFMA16(WizA[2][1], hrB, Dn); Dn = MFMA16(WizA[2][2], hlB, Dn);
          Dr = MFMA16(WhzA[0], hzB, Dr);
          Dz = MFMA16(WhzA[1], hzB, Dz);
          Dh = MFMA16(WhzA[2], hzB, Dh);
          Dr = MFMA16(WizA[0][0], zB, Dr);
          Dz = MFMA16(WizA[1][0], zB, Dz);
          Dn = MFMA16(WizA[2][0], zB, Dn);
          gru_update(Dr, Dz, Dn, Dh, hzB);
          *(half4v*)(hz + (((size_t)i*Bb + base + r) << 4) + q*4) = hzB;

          float4v H1 = {bI1v[0],bI1v[1],bI1v[2],bI1v[3]};
          H1 = MFMA16(I1A, hzB, H1);
          const half4v h1B = relu_pack(H1);
          float4v H2 = {bI2v[0],bI2v[1],bI2v[2],bI2v[3]};
          H2 = MFMA16(I2A, h1B, H2);
          const half4v h2B = relu_pack(H2);
          float4v Qmu  = {bIMu[0],bIMu[1],bIMu[2],bIMu[3]};
          float4v Qpre = {bICov[0],bICov[1],bICov[2],bICov[3]};
          Qmu  = MFMA16(IMuA,  h2B, Qmu);
          Qpre = MFMA16(ICovA, h2B, Qpre);

          #pragma unroll
          for (int ii = 0; ii < 4; ++ii){
            const float qs = __expf(Qpre[ii]);
            zB[ii] = (_Float16)(Qmu[ii] + qs*ev[ii]);
          }
          union { half4v h; u32 u[2]; } zc; zc.h = zB;
          const int slot = i & 7;
          zS[slot][0][l] = zc.u[0];
          zS[slot][1][l] = zc.u[1];
        }
      } else if (w == 1){
        if (i >= 2 && i < Tt + 2){
          const int s = i - 2;
          union { half4v h; u32 u[2]; } zc;
          const int sp = (s - 1) & 7;
          zc.u[0] = zS[sp][0][l]; zc.u[1] = zS[sp][1][l];
          const half4v zPrev = zc.h;

          float4v Er = {bg0[0],bg0[1],bg0[2],bg0[3]};
          float4v Ez = {bg1[0],bg1[1],bg1[2],bg1[3]};
          float4v En = {bgn[0],bgn[1],bgn[2],bgn[3]};
          float4v Eh = {bgh[0],bgh[1],bgh[2],bgh[3]};
          Er = MFMA16(WgzA[0], zPrev, Er); Er = MFMA16(WhgzA[0], hgzB, Er);
          Ez = MFMA16(WgzA[1], zPrev, Ez); Ez = MFMA16(WhgzA[1], hgzB, Ez);
          En = MFMA16(WgzA[2], zPrev, En);
          Eh = MFMA16(WhgzA[2], hgzB, Eh);
          gru_update(Er, Ez, En, Eh, hgzB);
          *(half4v*)(hgz + (((size_t)s*Bb + base + r) << 4) + q*4) = hgzB;
        }
      } else {
        if (i >= 4 && i < Tt + 4){
          const int u = i - 4;
          union { half4v h; u32 uu[2]; } zc;
          const int su = u & 7;
          zc.uu[0] = zS[su][0][l]; zc.uu[1] = zS[su][1][l];
          const half4v zU = zc.h;

          float4v Fr = {br0[0],br0[1],br0[2],br0[3]};
          float4v Fz = {br1[0],br1[1],br1[2],br1[3]};
          float4v Fn = {brn[0],brn[1],brn[2],brn[3]};
          float4v Fh = {brh[0],brh[1],brh[2],brh[3]};
          Fr = MFMA16(WgrA[0], zU, Fr); Fr = MFMA16(WhgrA[0], hgrB, Fr);
          Fz = MFMA16(WgrA[1], zU, Fz); Fz = MFMA16(WhgrA[1], hgrB, Fz);
          Fn = MFMA16(WgrA[2], zU, Fn);
          Fh = MFMA16(WhgrA[2], hgrB, Fh);
          gru_update(Fr, Fz, Fn, Fh, hgrB);
          *(half4v*)(hgr + (((size_t)u*Bb + base + r) << 4) + q*4) = hgrB;
        }
      }
      if (k & 1) barrier_lds();
    }
  }
}

// ================= Phase 3b: merged parallel epilogue — NO atomics =================
// Blocks [0,1024): KL; [1024,2048): NLL. Per-block partial sums go to red[] in
// workspace (contention-free); a final 1-block kernel reduces. This removes the
// 4096 serialized same-cacheline atomicAdds that dominated epi's runtime.
__global__ __launch_bounds__(256,2) void epi(InPtrs ip, const _Float16* __restrict__ hz,
                                             const _Float16* __restrict__ hgz,
                                             const _Float16* __restrict__ hgr,
                                             float* __restrict__ red)
{
  const int tid = threadIdx.x;
  const int l = tid & 63, r = l & 15, q = l >> 4;
  const int row0 = q*4;
  __shared__ float sred[4];

  if (blockIdx.x < 1024){
    const int wid = blockIdx.x * 4 + (tid >> 6);
    const int u0 = wid * 16;

    half4v I1A, I2A, IMuA, ICovA, Z1A, Z2A, ZMuA, ZCovA;
    float bI1v[4], bI2v[4], bIMu[4], bICov[4], bZ1v[4], bZ2v[4], bZMu[4], bZCov[4];
    #pragma unroll
    for (int j = 0; j < 4; ++j){
      const int k = q*4 + j;
      I1A[j]  = (_Float16)ip.p[14][r*16 + k];
      I2A[j]  = (_Float16)ip.p[16][r*16 + k];
      IMuA[j] = (r < 10) ? (_Float16)ip.p[18][r*16 + k] : (_Float16)0.f;
      ICovA[j]= (r < 10) ? (_Float16)ip.p[20][r*16 + k] : (_Float16)0.f;
      Z1A[j]  = (_Float16)ip.p[26][r*16 + k];
      Z2A[j]  = (_Float16)ip.p[28][r*16 + k];
      ZMuA[j] = (r < 10) ? (_Float16)ip.p[30][r*16 + k] : (_Float16)0.f;
      ZCovA[j]= (r < 10) ? (_Float16)ip.p[32][r*16 + k] : (_Float16)0.f;
    }
    #pragma unroll
    for (int i = 0; i < 4; ++i){
      const int row = row0 + i;
      bI1v[i] = ip.p[15][row];  bI2v[i] = ip.p[17][row];
      bIMu[i]  = (row < 10) ? ip.p[19][row] : 0.f;
      bICov[i] = (row < 10) ? ip.p[21][row] : 0.f;
      bZ1v[i] = ip.p[27][row];  bZ2v[i] = ip.p[29][row];
      bZMu[i]  = (row < 10) ? ip.p[31][row] : 0.f;
      bZCov[i] = (row < 10) ? ip.p[33][row] : 0.f;
    }

    float kl_acc = 0.f;
    for (int k = 0; k < 16; ++k){
      const int u = u0 + k;
      const int tile = u >> 9, t = u & 511;
      const size_t off = (((size_t)t*Bb + tile*16 + r) << 4) + q*4;
      const half4v hzB  = *(const half4v*)(hz  + off);
      const half4v hgzB = *(const half4v*)(hgz + off);

      float4v H1 = {bI1v[0],bI1v[1],bI1v[2],bI1v[3]};
      H1 = MFMA16(I1A, hzB, H1);
      const half4v h1B = relu_pack(H1);
      float4v H2 = {bI2v[0],bI2v[1],bI2v[2],bI2v[3]};
      H2 = MFMA16(I2A, h1B, H2);
      const half4v h2B = relu_pack(H2);
      float4v Qmu  = {bIMu[0],bIMu[1],bIMu[2],bIMu[3]};
      float4v Qpre = {bICov[0],bICov[1],bICov[2],bICov[3]};
      Qmu  = MFMA16(IMuA,  h2B, Qmu);
      Qpre = MFMA16(ICovA, h2B, Qpre);

      float4v G1 = {bZ1v[0],bZ1v[1],bZ1v[2],bZ1v[3]};
      G1 = MFMA16(Z1A, hgzB, G1);
      const half4v g1B = relu_pack(G1);
      float4v G2 = {bZ2v[0],bZ2v[1],bZ2v[2],bZ2v[3]};
      G2 = MFMA16(Z2A, g1B, G2);
      const half4v g2B = relu_pack(G2);
      float4v Pmu  = {bZMu[0],bZMu[1],bZMu[2],bZMu[3]};
      float4v Ppre = {bZCov[0],bZCov[1],bZCov[2],bZCov[3]};
      Pmu  = MFMA16(ZMuA,  g2B, Pmu);
      Ppre = MFMA16(ZCovA, g2B, Ppre);

      #pragma unroll
      for (int ii = 0; ii < 4; ++ii){
        const float qs = __expf(Qpre[ii]);
        const float dm = Qmu[ii] - Pmu[ii];
        kl_acc += (Ppre[ii] - Qpre[ii]) + (qs*qs + dm*dm)*0.5f*__expf(-2.f*Ppre[ii]) - 0.5f;
      }
    }
    #pragma unroll
    for (int m = 1; m < 64; m <<= 1) kl_acc += __shfl_xor(kl_acc, m, 64);
    if (l == 0) sred[tid >> 6] = kl_acc;
    __syncthreads();
    if (tid == 0) red[blockIdx.x] = sred[0] + sred[1] + sred[2] + sred[3];
  } else {
    const int wid = (blockIdx.x - 1024) * 4 + (tid >> 6);
    const int u0 = wid * 16;

    half4v R1A, R2A[12];
    float bR1v[4], bR2v[12][4];
    #pragma unroll
    for (int j = 0; j < 4; ++j){
      const int k = q*4 + j;
      R1A[j] = (_Float16)ip.p[38][r*16 + k];
      #pragma unroll
      for (int m = 0; m < 12; ++m)
        R2A[m][j] = (_Float16)ip.p[40][(m*16 + r)*16 + k];
    }
    #pragma unroll
    for (int i = 0; i < 4; ++i){
      const int row = row0 + i;
      bR1v[i] = ip.p[39][row];
      #pragma unroll
      for (int m = 0; m < 12; ++m) bR2v[m][i] = ip.p[41][m*16 + row];
    }

    float nll_acc = 0.f;
    for (int k = 0; k < 16; ++k){
      const int u = u0 + k;
      const int tile = u >> 9, t = u & 511;
      const half4v hgrB = *(const half4v*)(hgr + (((size_t)t*Bb + tile*16 + r) << 4) + q*4);
      const float* xrow = ip.p[0] + ((size_t)(tile*16 + r) * Tt + t) * 64;
      float4v xv[4];
      #pragma unroll
      for (int m = 0; m < 4; ++m) xv[m] = *(const float4v*)(xrow + m*16 + q*4);

      float4v R1D = {bR1v[0],bR1v[1],bR1v[2],bR1v[3]};
      R1D = MFMA16(R1A, hgrB, R1D);
      const half4v r1B = relu_pack(R1D);

      float s1 = 0.f, s2 = 0.f, s3 = 0.f, s4 = 0.f;
      #pragma unroll
      for (int m = 0; m < 4; ++m){
        float4v Dmu = {bR2v[m][0],bR2v[m][1],bR2v[m][2],bR2v[m][3]};
        float4v Ddp = {bR2v[4+m][0],bR2v[4+m][1],bR2v[4+m][2],bR2v[4+m][3]};
        float4v Dw  = {bR2v[8+m][0],bR2v[8+m][1],bR2v[8+m][2],bR2v[8+m][3]};
        Dmu = MFMA16(R2A[m],   r1B, Dmu);
        Ddp = MFMA16(R2A[4+m], r1B, Ddp);
        Dw  = MFMA16(R2A[8+m], r1B, Dw);
        #pragma unroll
        for (int ii = 0; ii < 4; ++ii){
          const float diag = __expf(Ddp[ii]) + 1e-4f;
          const float dinv = rcpf(diag);
          const float delta = xv[m][ii] - Dmu[ii];
          const float wv = Dw[ii];
          s1 += delta*delta*dinv;
          s2 += wv*wv*dinv;
          s3 += wv*dinv*delta;
          s4 += __logf(diag);
        }
      }
      s1 += __shfl_xor(s1, 16, 64); s1 += __shfl_xor(s1, 32, 64);
      s2 += __shfl_xor(s2, 16, 64); s2 += __shfl_xor(s2, 32, 64);
      s3 += __shfl_xor(s3, 16, 64); s3 += __shfl_xor(s3, 32, 64);
      s4 += __shfl_xor(s4, 16, 64); s4 += __shfl_xor(s4, 32, 64);
      const float cap = 1.f + s2;
      const float maha = s1 - s3*s3*rcpf(cap);
      const float logdet = s4 + __logf(cap);
      nll_acc += 0.5f*(64.f*LOG2PI_ + logdet + maha);
    }
    #pragma unroll
    for (int m = 1; m < 64; m <<= 1) nll_acc += __shfl_xor(nll_acc, m, 64);
    if (l == 0) sred[tid >> 6] = nll_acc;
    __syncthreads();
    if (tid == 0) red[blockIdx.x] = sred[0] + sred[1] + sred[2] + sred[3];
  }
}

// ================= final reduction: 2048 partials -> out[0..1] =================
__global__ __launch_bounds__(256,1) void finred(const float* __restrict__ red,
                                                float* __restrict__ out)
{
  const int tid = threadIdx.x;
  float a = 0.f, b = 0.f;
  for (int i = tid; i < 1024; i += 256){
    a += red[i];          // KL partials
    b += red[1024 + i];   // NLL partials
  }
  #pragma unroll
  for (int m = 1; m < 64; m <<= 1){
    a += __shfl_xor(a, m, 64);
    b += __shfl_xor(b, m, 64);
  }
  __shared__ float sa[4], sb[4];
  if ((tid & 63) == 0){ sa[tid >> 6] = a; sb[tid >> 6] = b; }
  __syncthreads();
  if (tid == 0){
    out[1] = (sa[0] + sa[1] + sa[2] + sa[3]) * (1.f/(float)Bb);
    out[0] = (sb[0] + sb[1] + sb[2] + sb[3]) * 0.25f * (1.f/(float)Bb);
  }
}

} // namespace

extern "C" void kernel_launch(void* const* d_in, const int* in_sizes, int n_in,
                              void* d_out, int out_size, void* d_ws, size_t ws_size,
                              hipStream_t stream)
{
  InPtrs ip;
  for (int i = 0; i < 42; ++i) ip.p[i] = (const float*)d_in[i];
  float* out = (float*)d_out;

  const size_t SZ = (size_t)Tt * Bb * 16;
  _Float16* hf  = (_Float16*)d_ws;
  _Float16* hb  = hf  + SZ;
  _Float16* hz  = hb  + SZ;
  _Float16* hgz = hz  + SZ;
  _Float16* hgr = hgz + SZ;
  float* red    = (float*)(hgr + SZ);   // 2048 floats

  dim3 gb(Bb/16, 2);
  bigru<<<gb, 128, 0, stream>>>(ip, hf, hb);
  vae_seq<<<Bb/16, 192, 0, stream>>>(ip, hf, hb, hz, hgz, hgr);
  epi<<<2048, 256, 0, stream>>>(ip, hz, hgz, hgr, red);
  finred<<<1, 256, 0, stream>>>(red, out);
}